// Round 15
// baseline (375.633 us; speedup 1.0000x reference)
//
#include <hip/hip_runtime.h>
#include <hip/hip_bf16.h>

// GCN_71451075936314 on gfx950.
// R24: (a) lstm Hs packed writes: remap hcol = w*8 + quad*2 + gt (bijective;
//      all Hs consumers read whole octets) so a thread's two gt-cells are
//      adjacent -> 4 x ds_write_b32 instead of 8 x ds_write_b16 per thread
//      per step. Touch points: ggemm gbase decode, Whh wr, cell write.
//      (b) pool_final re-merged via vmcnt-ticket. R21's +29us re-diagnosed:
//      __threadfence (wbl2) x782 AND tail LDS +6.6KB dropped aggru 4->3
//      blocks/CU. Now: lane-0 s_waitcnt vmcnt(0) only (atomics are
//      device-coherent once complete; barrier orders the block) + tail
//      reuses dead Ag/H2 LDS. 4 dispatches total.
//      R23 baseline: 363.2us = lstm 174.5 + rest ~189.

#define NN     50000
#define HIDD   128
#define MAXD   16
#define NGRAPH 50
#define NCLSS  10
#define GRUH   32

typedef __attribute__((ext_vector_type(8))) short s16x8;    // 8 bf16 (4 VGPRs)
typedef __attribute__((ext_vector_type(4))) float f32x4;
typedef __hip_bfloat16 bf16;

#define MFMA16(a,b,c)  __builtin_amdgcn_mfma_f32_16x16x32_bf16((a),(b),(c),0,0,0)

__device__ __forceinline__ float bf2f(bf16 x) { return __bfloat162float(x); }
__device__ __forceinline__ bf16  f2bf(float x) { return __float2bfloat16(x); }
__device__ __forceinline__ s16x8 ldfrag(const bf16* p) { return *(const s16x8*)p; }

__device__ __forceinline__ s16x8 ldfrag_f32(const float* p) {
  const float4 a = *(const float4*)p;
  const float4 b = *(const float4*)(p + 4);
  union { s16x8 v; bf16 h[8]; } r;
  r.h[0] = f2bf(a.x); r.h[1] = f2bf(a.y); r.h[2] = f2bf(a.z); r.h[3] = f2bf(a.w);
  r.h[4] = f2bf(b.x); r.h[5] = f2bf(b.y); r.h[6] = f2bf(b.z); r.h[7] = f2bf(b.w);
  return r.v;
}

__device__ __forceinline__ float sigf(float x) {
  return __builtin_amdgcn_rcpf(1.0f + __expf(-x));
}
__device__ __forceinline__ float tanhf_(float x) {
  return 1.0f - 2.0f * __builtin_amdgcn_rcpf(1.0f + __expf(2.0f * x));
}

__device__ __forceinline__ unsigned packbf2(float a, float b) {
  union { bf16 h; unsigned short u; } x, y;
  x.h = f2bf(a); y.h = f2bf(b);
  return (unsigned)x.u | ((unsigned)y.u << 16);
}
__device__ __forceinline__ float lo2f(unsigned u) { return __uint_as_float(u << 16); }
__device__ __forceinline__ float hi2f(unsigned u) { return __uint_as_float(u & 0xffff0000u); }

// barrier that drains LDS ops only — global loads stay in flight
__device__ __forceinline__ void lgkm_barrier() {
  asm volatile("s_waitcnt lgkmcnt(0)\n\ts_barrier" ::: "memory");
}

// ------- prep: weight casts/transposes + bias fold + partial hist + zeroing -------
__global__ __launch_bounds__(256) void prep_kernel(const float* __restrict__ Wih,
                            const float* __restrict__ Whh, const float* __restrict__ bih,
                            const float* __restrict__ bhh, const float* __restrict__ Wself,
                            const float* __restrict__ Wneigh, const float* __restrict__ Wgc,
                            const float* __restrict__ Wgru, const int* __restrict__ deg,
                            bf16* WihB, bf16* WhhB, bf16* WsT, bf16* WnT,
                            bf16* WgT, bf16* WgruB, float* biasS,
                            int* histp, int* resv, float* psums, int* done) {
  __shared__ int lh[17];
  const int tid = threadIdx.x;
  if (blockIdx.x < 196) {
    if (tid < 17) lh[tid] = 0;
    __syncthreads();
    const int i = blockIdx.x * 256 + tid;
    if (i < NN) atomicAdd(&lh[deg[i]], 1);
    __syncthreads();
    if (tid < 17) histp[blockIdx.x * 17 + tid] = lh[tid];
  }
  if (blockIdx.x == 0) {
    for (int i = tid; i < 17; i += 256) resv[i] = 0;
    for (int i = tid; i < NGRAPH * GRUH + NGRAPH; i += 256) psums[i] = 0.f;
    if (tid == 0) *done = 0;
  }
  const int total = 2 * 65536 + 3 * 16384 + 12288 + 512;   // 193024
  int stride = gridDim.x * blockDim.x;
  for (int idx = blockIdx.x * blockDim.x + threadIdx.x; idx < total; idx += stride) {
    int j = idx;
    if (j < 65536) { WihB[j] = f2bf(Wih[j]); continue; }
    j -= 65536;
    if (j < 65536) { WhhB[j] = f2bf(Whh[j]); continue; }
    j -= 65536;
    if (j < 16384) { int c = j >> 7, k = j & 127; WsT[j] = f2bf(Wself[k * HIDD + c]); continue; }
    j -= 16384;
    if (j < 16384) { int c = j >> 7, k = j & 127; WnT[j] = f2bf(Wneigh[k * HIDD + c]); continue; }
    j -= 16384;
    if (j < 16384) { int c = j >> 7, k = j & 127; WgT[j] = f2bf(Wgc[k * HIDD + c]); continue; }
    j -= 16384;
    if (j < 12288) { WgruB[j] = f2bf(Wgru[j]); continue; }
    j -= 12288;
    biasS[j] = bih[j] + bhh[j];
  }
}

// ------- sg: blocks 0..781 = G-GEMM; blocks 782..977 = scatter (counting sort) -------
__global__ __launch_bounds__(256) void sg_kernel(const float* __restrict__ featF,
                                                 const bf16* __restrict__ WihB,
                                                 const float* __restrict__ biasS,
                                                 bf16* __restrict__ Gp,
                                                 const int* __restrict__ deg,
                                                 const int* __restrict__ histp,
                                                 int* __restrict__ resv,
                                                 int* __restrict__ perm) {
  const int tid = threadIdx.x;
  if (blockIdx.x >= 782) {
    // ---------------- scatter (counting sort by degree, DESCENDING) ----------------
    __shared__ int lh[17], lbase[17], lpos[17], gh[17];
    const int sb = blockIdx.x - 782;
    if (tid < 17) { lh[tid] = 0; lpos[tid] = 0; }
    __syncthreads();
    const int i = sb * 256 + tid;
    const int d = (i < NN) ? deg[i] : -1;
    if (d >= 0) atomicAdd(&lh[d], 1);
    __syncthreads();
    if (tid < 17) {
      int s = 0;
      for (int b = 0; b < 196; ++b) s += histp[b * 17 + tid];
      gh[tid] = s;
    }
    __syncthreads();
    if (tid < 17) {
      int pre = 0;
      for (int k = tid + 1; k < 17; ++k) pre += gh[k];   // descending: larger degs first
      lbase[tid] = pre + (lh[tid] ? atomicAdd(&resv[tid], lh[tid]) : 0);
    }
    __syncthreads();
    if (d >= 0) {
      const int p = lbase[d] + atomicAdd(&lpos[d], 1);
      perm[p] = i;
    }
    return;
  }
  // ---------------- G-GEMM: 2 passes of 32 rows through LDS, coalesced write ----------------
  __shared__ __align__(16) bf16 Gs[32][520];    // 33.3KB, pad 520
  const int lane = tid & 63, wave = tid >> 6;
  const int l15 = lane & 15, quad = lane >> 4;
  const int nb = blockIdx.x * 64;

  s16x8 Bx[4][4];
#pragma unroll
  for (int nt = 0; nt < 4; ++nt) {
    int arow = nb + nt * 16 + l15; if (arow >= NN) arow = NN - 1;
#pragma unroll
    for (int kt = 0; kt < 4; ++kt)
      Bx[nt][kt] = ldfrag_f32(featF + (size_t)arow * HIDD + kt * 32 + quad * 8);
  }

#pragma unroll
  for (int pass = 0; pass < 2; ++pass) {
    for (int hg = wave * 8; hg < wave * 8 + 8; ++hg) {
      const int wr = (l15 & 3) * HIDD + hg * 4 + (l15 >> 2);
      s16x8 Aw[4];
#pragma unroll
      for (int kt = 0; kt < 4; ++kt)
        Aw[kt] = ldfrag(WihB + (size_t)wr * HIDD + kt * 32 + quad * 8);
      const int hcol = hg * 4 + quad;
      // NEW packed layout: hcol = w*8 + q*2 + gt  ->  w=hcol>>3, q=(hcol>>1)&3, gt=hcol&1
      const int gbase = (hcol >> 3) * 32 + ((hcol >> 1) & 3) * 8 + (hcol & 1) * 4;
      float b0 = biasS[0 * HIDD + hcol], b1 = biasS[1 * HIDD + hcol];
      float b2 = biasS[2 * HIDD + hcol], b3 = biasS[3 * HIDD + hcol];
#pragma unroll
      for (int nt2 = 0; nt2 < 2; ++nt2) {
        const int nt = pass * 2 + nt2;
        f32x4 acc = {0.f, 0.f, 0.f, 0.f};
#pragma unroll
        for (int kt = 0; kt < 4; ++kt)
          acc = MFMA16(Aw[kt], Bx[nt][kt], acc);
        unsigned u0 = packbf2(acc[0] + b0, acc[1] + b1);
        unsigned u1 = packbf2(acc[2] + b2, acc[3] + b3);
        *(uint2*)(&Gs[nt2 * 16 + l15][gbase]) = make_uint2(u0, u1);
      }
    }
    __syncthreads();
    for (int e = tid; e < 2048; e += 256) {
      const int r = e >> 6, off = (e & 63) * 8;
      const int node = nb + pass * 32 + r;
      if (node < NN)
        *(s16x8*)(Gp + (size_t)node * 512 + off) = *(const s16x8*)(&Gs[r][off]);
    }
    __syncthreads();
  }
}

// ---------------- LSTM recurrence + fused SAGE epilogue ----------------
// 1024 thr / 16 waves / 64 nodes. Packed-G'' single 16B gather per node per
// thread; hcol = w*8 + quad*2 + gt remap -> packed b32 Hs writes.
__global__ __launch_bounds__(1024, 4) void lstm_kernel(const bf16* __restrict__ Gp,
                                                       const bf16* __restrict__ WhhB,
                                                       const float* __restrict__ featF,
                                                       const bf16* __restrict__ WsT,
                                                       const bf16* __restrict__ WnT,
                                                       const float* __restrict__ b_sage,
                                                       const int* __restrict__ nbr_idx,
                                                       const int* __restrict__ deg,
                                                       const int* __restrict__ perm,
                                                       bf16* __restrict__ h1n) {
  __shared__ __align__(16) bf16 Hs[2][64 * 128];  // 32KB: h dbuf, oct-xor swizzled
  __shared__ int nbr_s[16 * 64];                  // [t][row]
  __shared__ int nodes_s[64];
  __shared__ int degs_s[64];

  const int tid = threadIdx.x;
  const int lane = tid & 63, w = tid >> 6;        // w = hcol-block 0..15
  const int l15 = lane & 15, quad = lane >> 4;
  const int base = blockIdx.x * 64;

  if (tid < 64) {
    const int gi = base + tid;
    const int nd = (gi < NN) ? perm[gi] : -1;
    nodes_s[tid] = nd;
    degs_s[tid] = (nd >= 0) ? deg[nd] : 0;
  }
  __syncthreads();
  {
    const int row = tid & 63, t = tid >> 6;       // exactly one entry per thread
    const int nd = nodes_s[row];
    nbr_s[t * 64 + row] = (nd >= 0) ? nbr_idx[nd * MAXD + t] : 0;
  }

  // pinned Whh packed frags: vrow v=l15 -> Whh row (v&3)*128 + w*8 + (v>>2)*2 + gt
  s16x8 Bh[2][4];
#pragma unroll
  for (int gt = 0; gt < 2; ++gt) {
    const int wr = (l15 & 3) * HIDD + w * 8 + (l15 >> 2) * 2 + gt;
#pragma unroll
    for (int kt = 0; kt < 4; ++kt) {
      Bh[gt][kt] = ldfrag(WhhB + (size_t)wr * HIDD + kt * 32 + quad * 8);
      asm volatile("" : "+v"(Bh[gt][kt]));
    }
  }

  __syncthreads();                                // nbr_s visible
  const int maxdeg = degs_s[0];                   // descending sort -> block max

  int mydeg[4];
#pragma unroll
  for (int nt = 0; nt < 4; ++nt) mydeg[nt] = degs_s[nt * 16 + l15];

  // per-thread packed G'' element offset (16B = both gt chunks)
  const int gofs = w * 32 + quad * 8;

  float cst[2][4] = {{0.f, 0.f, 0.f, 0.f}, {0.f, 0.f, 0.f, 0.f}};
  float hprev[2][4] = {{0.f, 0.f, 0.f, 0.f}, {0.f, 0.f, 0.f, 0.f}};

  for (int t = 0; t < maxdeg; ++t) {
    const int cur = t & 1, nxt = cur ^ 1;

    // gather x-gates: ONE 16B load per node
    uint2 gx[2][4];
#pragma unroll
    for (int nt = 0; nt < 4; ++nt) {
      const int nb1 = nbr_s[t * 64 + nt * 16 + l15];
      const uint4 g4 = *(const uint4*)(Gp + (size_t)nb1 * 512 + gofs);
      gx[0][nt] = make_uint2(g4.x, g4.y);
      gx[1][nt] = make_uint2(g4.z, g4.w);
    }

    f32x4 acc[2][4];
#pragma unroll
    for (int gt = 0; gt < 2; ++gt)
#pragma unroll
      for (int nt = 0; nt < 4; ++nt) acc[gt][nt] = (f32x4){0.f, 0.f, 0.f, 0.f};

    // h-part: gates += Whh_packed @ h^T  (skip at t=0: h0 = 0)
    if (t > 0) {
      __builtin_amdgcn_s_setprio(1);
#pragma unroll
      for (int kt = 0; kt < 4; ++kt) {
#pragma unroll
        for (int nt = 0; nt < 4; ++nt) {
          const int row = nt * 16 + l15;
          const s16x8 ah = ldfrag(Hs[cur] + row * 128 + (((kt * 4 + quad) ^ l15) * 8));
#pragma unroll
          for (int gt = 0; gt < 2; ++gt)
            acc[gt][nt] = MFMA16(Bh[gt][kt], ah, acc[gt][nt]);
        }
      }
      __builtin_amdgcn_s_setprio(0);
    }

    // elementwise cell (7-trans form); packed b32 write of both gt cells
#pragma unroll
    for (int nt = 0; nt < 4; ++nt) {
      const int row = nt * 16 + l15;
      const bool act = (t < mydeg[nt]);
      float hnv[2];
#pragma unroll
      for (int gt = 0; gt < 2; ++gt) {
        const uint2 g = gx[gt][nt];
        const float g_i = acc[gt][nt][0] + lo2f(g.x);
        const float g_f = acc[gt][nt][1] + hi2f(g.x);
        const float g_g = acc[gt][nt][2] + lo2f(g.y);
        const float g_o = acc[gt][nt][3] + hi2f(g.y);
        const float Ae = __expf(-g_i);
        const float Fe = __expf(-g_f);
        const float Be = __expf(-2.f * g_g);
        const float Ce = __expf(-g_o);
        const float Qf = 1.f + Fe;
        const float P  = (1.f + Ae) * (1.f + Be);
        const float num = cst[gt][nt] * P + (1.f - Be) * Qf;
        const float cn = num * __builtin_amdgcn_rcpf(Qf * P);
        const float De = __expf(-2.f * cn);
        const float hn_new =
            (1.f - De) * __builtin_amdgcn_rcpf((1.f + Ce) * (1.f + De));
        if (act) cst[gt][nt] = cn;
        const float hn = act ? hn_new : hprev[gt][nt];
        hprev[gt][nt] = hn;
        hnv[gt] = hn;
      }
      *(unsigned*)(&Hs[nxt][row * 128 + ((w ^ (row & 15)) * 8) + quad * 2]) =
          packbf2(hnv[0], hnv[1]);
    }
    lgkm_barrier();   // single barrier: dbuf writes visible, reads done
  }

  // ---- fused SAGE epilogue: h1n = relu(feat@Ws + hT@Wn + b) * rsqrt(deg) ----
  const bf16* Hf = Hs[maxdeg & 1];
  {
    const int rq = w & 3, cp = w >> 2;
    const int rowA = rq * 16 + l15;               // A-frag row (m index)
    const int ndA = nodes_s[rowA];
    const int ndA2 = (ndA >= 0) ? ndA : 0;        // garbage rows never written
    s16x8 Fa[4], Ha[4];
#pragma unroll
    for (int kt = 0; kt < 4; ++kt) {
      Fa[kt] = ldfrag_f32(featF + (size_t)ndA2 * HIDD + kt * 32 + quad * 8);
      Ha[kt] = ldfrag(Hf + rowA * 128 + (((kt * 4 + quad) ^ l15) * 8));
    }
    int ndC[4]; float nrmC[4];
#pragma unroll
    for (int r = 0; r < 4; ++r) {
      const int rowC = rq * 16 + quad * 4 + r;
      ndC[r] = nodes_s[rowC];
      const int dd = degs_s[rowC];
      nrmC[r] = rsqrtf((float)((dd > 0) ? dd : 1));
    }
#pragma unroll
    for (int cc = 0; cc < 2; ++cc) {
      const int col = (cp * 2 + cc) * 16 + l15;
      f32x4 acc = {0.f, 0.f, 0.f, 0.f};
#pragma unroll
      for (int kt = 0; kt < 4; ++kt) {
        acc = MFMA16(Fa[kt], ldfrag(WsT + col * HIDD + kt * 32 + quad * 8), acc);
        acc = MFMA16(Ha[kt], ldfrag(WnT + col * HIDD + kt * 32 + quad * 8), acc);
      }
      const float bb = b_sage[col];
#pragma unroll
      for (int r = 0; r < 4; ++r)
        if (ndC[r] >= 0)
          h1n[(size_t)ndC[r] * HIDD + col] = f2bf(fmaxf(acc[r] + bb, 0.f) * nrmC[r]);
    }
  }
}

// ------- FUSED: agg gather -> gc GEMM -> GRU -> pool partial -> (last block) classifier -------
__global__ __launch_bounds__(256) void aggru_kernel(const bf16* __restrict__ h1n,
                                                    const int* __restrict__ nbr_idx,
                                                    const int* __restrict__ deg,
                                                    const int* __restrict__ gids,
                                                    const bf16* __restrict__ WgT,
                                                    const float* __restrict__ b_gc,
                                                    const bf16* __restrict__ WgruB,
                                                    const float* __restrict__ bih,
                                                    const float* __restrict__ bhh,
                                                    float* __restrict__ psums,
                                                    float* __restrict__ pcnts,
                                                    int* __restrict__ done,
                                                    const float* __restrict__ Wcls,
                                                    const float* __restrict__ bcls,
                                                    float* __restrict__ out) {
  __shared__ __align__(16) bf16 Ag[64 * 136];     // aggregated rows, padded pitch
  __shared__ __align__(16) bf16 H2[64 * 136];     // h2 tile, padded pitch
  __shared__ int nbrL[64 * 16];                   // [node][t] nbr lists
  __shared__ float psl[2 * GRUH];
  __shared__ float pcl[2];
  __shared__ int ticket_s;
  const int tid = threadIdx.x;
  const int lane = tid & 63, wave = tid >> 6;
  const int l15 = lane & 15, quad = lane >> 4;
  const int nbb = blockIdx.x * 64;
  const int nb = nbb + wave * 16;

  if (tid < 2 * GRUH) psl[tid] = 0.f;
  if (tid < 2) pcl[tid] = 0.f;

  // stage nbr lists (contiguous copy)
  for (int e = tid; e < 64 * 16; e += 256) {
    const int node = nbb + (e >> 4);
    nbrL[e] = (node < NN) ? nbr_idx[node * MAXD + (e & 15)] : 0;
  }
  __syncthreads();

  // phase A: node-parallel gather. thread -> (node = tid>>2, cols (tid&3)*32..+31)
  {
    const int myn = tid >> 2;
    const int node = nbb + myn;
    const int seg = (tid & 3) * 32;
    const int d = (node < NN) ? deg[node] : 0;
    float accv[32];
#pragma unroll
    for (int k = 0; k < 32; ++k) accv[k] = 0.f;
#pragma unroll 2
    for (int j = 0; j < d; ++j) {
      const int nbr = nbrL[myn * 16 + j];
      const bf16* rp = h1n + (size_t)nbr * HIDD + seg;
#pragma unroll
      for (int f = 0; f < 4; ++f) {
        union { s16x8 v; unsigned u[4]; } t_;
        t_.v = ldfrag(rp + f * 8);
#pragma unroll
        for (int p = 0; p < 4; ++p) {
          accv[f * 8 + 2 * p]     += lo2f(t_.u[p]);
          accv[f * 8 + 2 * p + 1] += hi2f(t_.u[p]);
        }
      }
    }
    const float nm = (d > 0) ? rsqrtf((float)d) : 0.f;
#pragma unroll
    for (int f = 0; f < 4; ++f) {
      union { s16x8 v; bf16 h[8]; } o;
#pragma unroll
      for (int k = 0; k < 8; ++k) o.h[k] = f2bf(accv[f * 8 + k] * nm);
      *(s16x8*)(Ag + myn * 136 + seg + f * 8) = o.v;
    }
  }
  __syncthreads();

  // phase B1: gc GEMM from Ag; h2 = relu(.) -> H2
  s16x8 A[4];
#pragma unroll
  for (int kt = 0; kt < 4; ++kt)
    A[kt] = ldfrag(Ag + (wave * 16 + l15) * 136 + kt * 32 + quad * 8);
  for (int ct = 0; ct < 8; ++ct) {
    const int col = ct * 16 + l15;
    f32x4 acc = {0.f, 0.f, 0.f, 0.f};
#pragma unroll
    for (int kt = 0; kt < 4; ++kt)
      acc = MFMA16(A[kt], ldfrag(WgT + col * HIDD + kt * 32 + quad * 8), acc);
    const float bb = b_gc[col];
#pragma unroll
    for (int r = 0; r < 4; ++r)
      H2[(wave * 16 + quad * 4 + r) * 136 + col] = f2bf(fmaxf(acc[r] + bb, 0.f));
  }
  __syncthreads();

  // phase B2: gru GEMM over rows wave*16 + l15
  s16x8 A2[4];
#pragma unroll
  for (int kt = 0; kt < 4; ++kt)
    A2[kt] = ldfrag(H2 + (wave * 16 + l15) * 136 + kt * 32 + quad * 8);
  f32x4 acc[6];
#pragma unroll
  for (int ct = 0; ct < 6; ++ct) {
    f32x4 a = {0.f, 0.f, 0.f, 0.f};
#pragma unroll
    for (int kt = 0; kt < 4; ++kt)
      a = MFMA16(A2[kt], ldfrag(WgruB + (ct * 16 + l15) * HIDD + kt * 32 + quad * 8), a);
    acc[ct] = a;
  }

  // phase C: gru activation + per-graph accumulate (block spans <=2 graphs)
  const int g0 = gids[nbb];
  int mynode[4], mygs[4];
#pragma unroll
  for (int r = 0; r < 4; ++r) {
    const int nd = nb + quad * 4 + r;
    mynode[r] = nd;
    mygs[r] = (nd < NN) ? (gids[nd] - g0) : 0;
  }
#pragma unroll
  for (int u = 0; u < 2; ++u) {
    const int cu = 16 * u + l15;
    const float br = bih[cu] + bhh[cu];
    const float bz = bih[32 + cu] + bhh[32 + cu];
    const float bni = bih[64 + cu];
    const float bnh = bhh[64 + cu];
#pragma unroll
    for (int r = 0; r < 4; ++r) {
      if (mynode[r] < NN) {
        const float rv = sigf(acc[u][r] + br);
        const float zv = sigf(acc[2 + u][r] + bz);
        const float nv = tanhf_(acc[4 + u][r] + bni + rv * bnh);
        const float v = (1.f - zv) * nv;
        atomicAdd(&psl[mygs[r] * GRUH + cu], v);
        if (u == 0 && l15 == 0) atomicAdd(&pcl[mygs[r]], 1.f);
      }
    }
  }
  __syncthreads();
  if (tid < 2 * GRUH) {
    const int s = tid >> 5, c = tid & 31;
    const float vv = psl[tid];
    if (vv != 0.f && g0 + s < NGRAPH) atomicAdd(&psums[(g0 + s) * GRUH + c], vv);
  }
  if (tid < 2) {
    if (pcl[tid] != 0.f && g0 + tid < NGRAPH) atomicAdd(&pcnts[g0 + tid], pcl[tid]);
  }

  // ---- vmcnt-only done-ticket: last block computes the classifier ----
  // (all flushing atomics were issued by wave 0; lane 0's s_waitcnt drains
  //  the whole wave's outstanding vmem, then the ticket RMW is ordered)
  if (tid == 0) {
    asm volatile("s_waitcnt vmcnt(0)" ::: "memory");
    ticket_s = atomicAdd(done, 1);
  }
  __syncthreads();
  if (ticket_s == (int)gridDim.x - 1) {
    float* ps = (float*)Ag;                       // reuse dead LDS (17.4KB)
    float* pc = (float*)H2;
    for (int i = tid; i < NGRAPH * GRUH; i += 256) ps[i] = atomicAdd(&psums[i], 0.f);
    for (int i = tid; i < NGRAPH; i += 256) pc[i] = atomicAdd(&pcnts[i], 0.f);
    __syncthreads();
    for (int idx = tid; idx < NGRAPH * NCLSS; idx += 256) {
      const int g = idx / NCLSS, k = idx % NCLSS;
      const float inv = 1.0f / pc[g];
      float a = bcls[k];
#pragma unroll
      for (int cc = 0; cc < GRUH; ++cc)
        a += ps[g * GRUH + cc] * inv * Wcls[cc * NCLSS + k];
      out[idx] = a;
    }
  }
}

extern "C" void kernel_launch(void* const* d_in, const int* in_sizes, int n_in,
                              void* d_out, int out_size, void* d_ws, size_t ws_size,
                              hipStream_t stream) {
  const float* feature  = (const float*)d_in[0];
  const int*   nbr_idx  = (const int*)d_in[1];
  const int*   deg      = (const int*)d_in[2];
  const int*   gids     = (const int*)d_in[3];
  const float* lstm_Wih = (const float*)d_in[4];
  const float* lstm_Whh = (const float*)d_in[5];
  const float* lstm_bih = (const float*)d_in[6];
  const float* lstm_bhh = (const float*)d_in[7];
  const float* W_self   = (const float*)d_in[8];
  const float* W_neigh  = (const float*)d_in[9];
  const float* b_sage   = (const float*)d_in[10];
  const float* W_gc     = (const float*)d_in[11];
  const float* b_gc     = (const float*)d_in[12];
  const float* Wih_gru  = (const float*)d_in[13];
  const float* bih_gru  = (const float*)d_in[14];
  const float* bhh_gru  = (const float*)d_in[15];
  const float* W_cls    = (const float*)d_in[16];
  const float* b_cls    = (const float*)d_in[17];

  // workspace: peak ~64.9 MB (within the 65.4 MB proven bound).
  char* ws = (char*)d_ws;
  bf16*  h1nB  = (bf16*)(ws + 0);           // [NN,128] 12.8MB
  bf16*  Gp    = (bf16*)(ws + 12800000);    // [NN,512] 51.2MB (dead after lstm)
  const size_t wo = 64000000;
  bf16*  WihB  = (bf16*)(ws + wo);
  bf16*  WhhB  = (bf16*)(ws + wo + 131072);
  bf16*  WsT   = (bf16*)(ws + wo + 262144);
  bf16*  WnT   = (bf16*)(ws + wo + 294912);
  bf16*  WgT   = (bf16*)(ws + wo + 327680);
  bf16*  WgruB = (bf16*)(ws + wo + 360448);
  float* biasS = (float*)(ws + wo + 385024);
  int*   perm  = (int*)(ws + 64500000);     // 200KB
  int*   histp = (int*)(ws + 64800000);     // [196*17] = 13.3KB
  int*   resv  = (int*)(ws + 64814000);     // [17]
  float* psums = (float*)(ws + 64815000);   // [50][32]
  float* pcnts = (float*)(ws + 64821400);   // [50]
  int*   done  = (int*)(ws + 64821600);     // [1]

  prep_kernel<<<754, 256, 0, stream>>>(lstm_Wih, lstm_Whh, lstm_bih, lstm_bhh,
                                       W_self, W_neigh, W_gc, Wih_gru, deg,
                                       WihB, WhhB, WsT, WnT, WgT, WgruB, biasS,
                                       histp, resv, psums, done);
  sg_kernel<<<978, 256, 0, stream>>>(feature, WihB, biasS, Gp, deg, histp, resv, perm);
  lstm_kernel<<<782, 1024, 0, stream>>>(Gp, WhhB, feature, WsT, WnT, b_sage,
                                        nbr_idx, deg, perm, h1nB);
  aggru_kernel<<<782, 256, 0, stream>>>(h1nB, nbr_idx, deg, gids, WgT, b_gc,
                                        WgruB, bih_gru, bhh_gru, psums, pcnts,
                                        done, W_cls, b_cls, (float*)d_out);
}

// Round 16
// 364.294 us; speedup vs baseline: 1.0311x; 1.0311x over previous
//
#include <hip/hip_runtime.h>
#include <hip/hip_bf16.h>

// GCN_71451075936314 on gfx950.
// R25: pure revert to R23 (measured best, 363.2us). R24 evidence: both
//      levers regressed. (a) packed b32 Hs writes halved bank conflicts
//      (1.7M->0.85M) but SLOWED lstm (174.5->177.5) — conflicts were
//      already hidden; the pack serialized the two gt chains. (b) the
//      vmcnt-ticket pool merge cost +9us (tail serialization + 782 RMWs
//      on one line > one dispatch gap); second failed attempt, idea dead.
// R23: 7-trans common-denominator LSTM cell (5 exps + 2 rcps/cell).
// R22: 5 dispatches: prep(+hist+zero), sg(scatter||ggemm), lstm(+SAGE),
//      aggru(agg+gc+gru+pool-partial), pool_final.
// lstm: 1024thr/64 nodes, Whh pinned packed vrows, G''-precompute with
//      single 16B gather per node per thread, oct-xor swizzled Hs dbuf.

#define NN     50000
#define HIDD   128
#define MAXD   16
#define NGRAPH 50
#define NCLSS  10
#define GRUH   32

typedef __attribute__((ext_vector_type(8))) short s16x8;    // 8 bf16 (4 VGPRs)
typedef __attribute__((ext_vector_type(4))) float f32x4;
typedef __hip_bfloat16 bf16;

#define MFMA16(a,b,c)  __builtin_amdgcn_mfma_f32_16x16x32_bf16((a),(b),(c),0,0,0)

__device__ __forceinline__ float bf2f(bf16 x) { return __bfloat162float(x); }
__device__ __forceinline__ bf16  f2bf(float x) { return __float2bfloat16(x); }
__device__ __forceinline__ s16x8 ldfrag(const bf16* p) { return *(const s16x8*)p; }

__device__ __forceinline__ s16x8 ldfrag_f32(const float* p) {
  const float4 a = *(const float4*)p;
  const float4 b = *(const float4*)(p + 4);
  union { s16x8 v; bf16 h[8]; } r;
  r.h[0] = f2bf(a.x); r.h[1] = f2bf(a.y); r.h[2] = f2bf(a.z); r.h[3] = f2bf(a.w);
  r.h[4] = f2bf(b.x); r.h[5] = f2bf(b.y); r.h[6] = f2bf(b.z); r.h[7] = f2bf(b.w);
  return r.v;
}

__device__ __forceinline__ float sigf(float x) {
  return __builtin_amdgcn_rcpf(1.0f + __expf(-x));
}
__device__ __forceinline__ float tanhf_(float x) {
  return 1.0f - 2.0f * __builtin_amdgcn_rcpf(1.0f + __expf(2.0f * x));
}

__device__ __forceinline__ unsigned packbf2(float a, float b) {
  union { bf16 h; unsigned short u; } x, y;
  x.h = f2bf(a); y.h = f2bf(b);
  return (unsigned)x.u | ((unsigned)y.u << 16);
}
__device__ __forceinline__ float lo2f(unsigned u) { return __uint_as_float(u << 16); }
__device__ __forceinline__ float hi2f(unsigned u) { return __uint_as_float(u & 0xffff0000u); }

// barrier that drains LDS ops only — global loads stay in flight
__device__ __forceinline__ void lgkm_barrier() {
  asm volatile("s_waitcnt lgkmcnt(0)\n\ts_barrier" ::: "memory");
}

// ------- prep: weight casts/transposes + bias fold + partial hist + zeroing -------
__global__ __launch_bounds__(256) void prep_kernel(const float* __restrict__ Wih,
                            const float* __restrict__ Whh, const float* __restrict__ bih,
                            const float* __restrict__ bhh, const float* __restrict__ Wself,
                            const float* __restrict__ Wneigh, const float* __restrict__ Wgc,
                            const float* __restrict__ Wgru, const int* __restrict__ deg,
                            bf16* WihB, bf16* WhhB, bf16* WsT, bf16* WnT,
                            bf16* WgT, bf16* WgruB, float* biasS,
                            int* histp, int* resv, float* psums) {
  __shared__ int lh[17];
  const int tid = threadIdx.x;
  if (blockIdx.x < 196) {
    if (tid < 17) lh[tid] = 0;
    __syncthreads();
    const int i = blockIdx.x * 256 + tid;
    if (i < NN) atomicAdd(&lh[deg[i]], 1);
    __syncthreads();
    if (tid < 17) histp[blockIdx.x * 17 + tid] = lh[tid];
  }
  if (blockIdx.x == 0) {
    for (int i = tid; i < 17; i += 256) resv[i] = 0;
    for (int i = tid; i < NGRAPH * GRUH + NGRAPH; i += 256) psums[i] = 0.f;
  }
  const int total = 2 * 65536 + 3 * 16384 + 12288 + 512;   // 193024
  int stride = gridDim.x * blockDim.x;
  for (int idx = blockIdx.x * blockDim.x + threadIdx.x; idx < total; idx += stride) {
    int j = idx;
    if (j < 65536) { WihB[j] = f2bf(Wih[j]); continue; }
    j -= 65536;
    if (j < 65536) { WhhB[j] = f2bf(Whh[j]); continue; }
    j -= 65536;
    if (j < 16384) { int c = j >> 7, k = j & 127; WsT[j] = f2bf(Wself[k * HIDD + c]); continue; }
    j -= 16384;
    if (j < 16384) { int c = j >> 7, k = j & 127; WnT[j] = f2bf(Wneigh[k * HIDD + c]); continue; }
    j -= 16384;
    if (j < 16384) { int c = j >> 7, k = j & 127; WgT[j] = f2bf(Wgc[k * HIDD + c]); continue; }
    j -= 16384;
    if (j < 12288) { WgruB[j] = f2bf(Wgru[j]); continue; }
    j -= 12288;
    biasS[j] = bih[j] + bhh[j];
  }
}

// ------- sg: blocks 0..781 = G-GEMM; blocks 782..977 = scatter (counting sort) -------
__global__ __launch_bounds__(256) void sg_kernel(const float* __restrict__ featF,
                                                 const bf16* __restrict__ WihB,
                                                 const float* __restrict__ biasS,
                                                 bf16* __restrict__ Gp,
                                                 const int* __restrict__ deg,
                                                 const int* __restrict__ histp,
                                                 int* __restrict__ resv,
                                                 int* __restrict__ perm) {
  const int tid = threadIdx.x;
  if (blockIdx.x >= 782) {
    // ---------------- scatter (counting sort by degree, DESCENDING) ----------------
    __shared__ int lh[17], lbase[17], lpos[17], gh[17];
    const int sb = blockIdx.x - 782;
    if (tid < 17) { lh[tid] = 0; lpos[tid] = 0; }
    __syncthreads();
    const int i = sb * 256 + tid;
    const int d = (i < NN) ? deg[i] : -1;
    if (d >= 0) atomicAdd(&lh[d], 1);
    __syncthreads();
    if (tid < 17) {
      int s = 0;
      for (int b = 0; b < 196; ++b) s += histp[b * 17 + tid];
      gh[tid] = s;
    }
    __syncthreads();
    if (tid < 17) {
      int pre = 0;
      for (int k = tid + 1; k < 17; ++k) pre += gh[k];   // descending: larger degs first
      lbase[tid] = pre + (lh[tid] ? atomicAdd(&resv[tid], lh[tid]) : 0);
    }
    __syncthreads();
    if (d >= 0) {
      const int p = lbase[d] + atomicAdd(&lpos[d], 1);
      perm[p] = i;
    }
    return;
  }
  // ---------------- G-GEMM: 2 passes of 32 rows through LDS, coalesced write ----------------
  __shared__ __align__(16) bf16 Gs[32][520];    // 33.3KB, pad 520
  const int lane = tid & 63, wave = tid >> 6;
  const int l15 = lane & 15, quad = lane >> 4;
  const int nb = blockIdx.x * 64;

  s16x8 Bx[4][4];
#pragma unroll
  for (int nt = 0; nt < 4; ++nt) {
    int arow = nb + nt * 16 + l15; if (arow >= NN) arow = NN - 1;
#pragma unroll
    for (int kt = 0; kt < 4; ++kt)
      Bx[nt][kt] = ldfrag_f32(featF + (size_t)arow * HIDD + kt * 32 + quad * 8);
  }

#pragma unroll
  for (int pass = 0; pass < 2; ++pass) {
    for (int hg = wave * 8; hg < wave * 8 + 8; ++hg) {
      const int wr = (l15 & 3) * HIDD + hg * 4 + (l15 >> 2);
      s16x8 Aw[4];
#pragma unroll
      for (int kt = 0; kt < 4; ++kt)
        Aw[kt] = ldfrag(WihB + (size_t)wr * HIDD + kt * 32 + quad * 8);
      const int hcol = hg * 4 + quad;
      const int gbase = (hcol >> 3) * 32 + (hcol & 3) * 8 + ((hcol >> 2) & 1) * 4;
      float b0 = biasS[0 * HIDD + hcol], b1 = biasS[1 * HIDD + hcol];
      float b2 = biasS[2 * HIDD + hcol], b3 = biasS[3 * HIDD + hcol];
#pragma unroll
      for (int nt2 = 0; nt2 < 2; ++nt2) {
        const int nt = pass * 2 + nt2;
        f32x4 acc = {0.f, 0.f, 0.f, 0.f};
#pragma unroll
        for (int kt = 0; kt < 4; ++kt)
          acc = MFMA16(Aw[kt], Bx[nt][kt], acc);
        unsigned u0 = packbf2(acc[0] + b0, acc[1] + b1);
        unsigned u1 = packbf2(acc[2] + b2, acc[3] + b3);
        *(uint2*)(&Gs[nt2 * 16 + l15][gbase]) = make_uint2(u0, u1);
      }
    }
    __syncthreads();
    for (int e = tid; e < 2048; e += 256) {
      const int r = e >> 6, off = (e & 63) * 8;
      const int node = nb + pass * 32 + r;
      if (node < NN)
        *(s16x8*)(Gp + (size_t)node * 512 + off) = *(const s16x8*)(&Gs[r][off]);
    }
    __syncthreads();
  }
}

// ---------------- LSTM recurrence + fused SAGE epilogue ----------------
// 1024 thr / 16 waves / 64 nodes. R13 recurrence; packed-G'' single 16B
// gather per node per thread. Cell uses 7-trans common-denominator form.
__global__ __launch_bounds__(1024, 4) void lstm_kernel(const bf16* __restrict__ Gp,
                                                       const bf16* __restrict__ WhhB,
                                                       const float* __restrict__ featF,
                                                       const bf16* __restrict__ WsT,
                                                       const bf16* __restrict__ WnT,
                                                       const float* __restrict__ b_sage,
                                                       const int* __restrict__ nbr_idx,
                                                       const int* __restrict__ deg,
                                                       const int* __restrict__ perm,
                                                       bf16* __restrict__ h1n) {
  __shared__ __align__(16) bf16 Hs[2][64 * 128];  // 32KB: h dbuf, oct-xor swizzled
  __shared__ int nbr_s[16 * 64];                  // [t][row]
  __shared__ int nodes_s[64];
  __shared__ int degs_s[64];

  const int tid = threadIdx.x;
  const int lane = tid & 63, w = tid >> 6;        // w = hcol-block 0..15
  const int l15 = lane & 15, quad = lane >> 4;
  const int base = blockIdx.x * 64;

  if (tid < 64) {
    const int gi = base + tid;
    const int nd = (gi < NN) ? perm[gi] : -1;
    nodes_s[tid] = nd;
    degs_s[tid] = (nd >= 0) ? deg[nd] : 0;
  }
  __syncthreads();
  {
    const int row = tid & 63, t = tid >> 6;       // exactly one entry per thread
    const int nd = nodes_s[row];
    nbr_s[t * 64 + row] = (nd >= 0) ? nbr_idx[nd * MAXD + t] : 0;
  }

  // pinned Whh packed frags: vrow v=l15 -> Whh row (v&3)*128 + w*8 + gt*4 + (v>>2)
  s16x8 Bh[2][4];
#pragma unroll
  for (int gt = 0; gt < 2; ++gt) {
    const int wr = (l15 & 3) * HIDD + w * 8 + gt * 4 + (l15 >> 2);
#pragma unroll
    for (int kt = 0; kt < 4; ++kt) {
      Bh[gt][kt] = ldfrag(WhhB + (size_t)wr * HIDD + kt * 32 + quad * 8);
      asm volatile("" : "+v"(Bh[gt][kt]));
    }
  }

  __syncthreads();                                // nbr_s visible
  const int maxdeg = degs_s[0];                   // descending sort -> block max

  int mydeg[4];
#pragma unroll
  for (int nt = 0; nt < 4; ++nt) mydeg[nt] = degs_s[nt * 16 + l15];

  // per-thread packed G'' element offset (16B = both gt chunks)
  const int gofs = w * 32 + quad * 8;

  float cst[2][4] = {{0.f, 0.f, 0.f, 0.f}, {0.f, 0.f, 0.f, 0.f}};
  float hprev[2][4] = {{0.f, 0.f, 0.f, 0.f}, {0.f, 0.f, 0.f, 0.f}};

  for (int t = 0; t < maxdeg; ++t) {
    const int cur = t & 1, nxt = cur ^ 1;

    // gather x-gates: ONE 16B load per node
    uint2 gx[2][4];
#pragma unroll
    for (int nt = 0; nt < 4; ++nt) {
      const int nb1 = nbr_s[t * 64 + nt * 16 + l15];
      const uint4 g4 = *(const uint4*)(Gp + (size_t)nb1 * 512 + gofs);
      gx[0][nt] = make_uint2(g4.x, g4.y);
      gx[1][nt] = make_uint2(g4.z, g4.w);
    }

    f32x4 acc[2][4];
#pragma unroll
    for (int gt = 0; gt < 2; ++gt)
#pragma unroll
      for (int nt = 0; nt < 4; ++nt) acc[gt][nt] = (f32x4){0.f, 0.f, 0.f, 0.f};

    // h-part: gates += Whh_packed @ h^T  (skip at t=0: h0 = 0)
    if (t > 0) {
      __builtin_amdgcn_s_setprio(1);
#pragma unroll
      for (int kt = 0; kt < 4; ++kt) {
#pragma unroll
        for (int nt = 0; nt < 4; ++nt) {
          const int row = nt * 16 + l15;
          const s16x8 ah = ldfrag(Hs[cur] + row * 128 + (((kt * 4 + quad) ^ l15) * 8));
#pragma unroll
          for (int gt = 0; gt < 2; ++gt)
            acc[gt][nt] = MFMA16(Bh[gt][kt], ah, acc[gt][nt]);
        }
      }
      __builtin_amdgcn_s_setprio(0);
    }

    // elementwise cell (7-trans common-denominator form):
    //   A=e^{-gi}, F=e^{-gf}, B=e^{-2gg}, C=e^{-go}
    //   c' = [c(1+A)(1+B) + (1-B)(1+F)] / [(1+F)(1+A)(1+B)]
    //   D=e^{-2c'}; h' = (1-D)/[(1+C)(1+D)]
#pragma unroll
    for (int gt = 0; gt < 2; ++gt) {
      const int col = w * 8 + gt * 4 + quad;
#pragma unroll
      for (int nt = 0; nt < 4; ++nt) {
        const int row = nt * 16 + l15;
        const uint2 g = gx[gt][nt];
        const float g_i = acc[gt][nt][0] + lo2f(g.x);
        const float g_f = acc[gt][nt][1] + hi2f(g.x);
        const float g_g = acc[gt][nt][2] + lo2f(g.y);
        const float g_o = acc[gt][nt][3] + hi2f(g.y);
        const float Ae = __expf(-g_i);
        const float Fe = __expf(-g_f);
        const float Be = __expf(-2.f * g_g);
        const float Ce = __expf(-g_o);
        const float Qf = 1.f + Fe;
        const float P  = (1.f + Ae) * (1.f + Be);
        const float num = cst[gt][nt] * P + (1.f - Be) * Qf;
        const float cn = num * __builtin_amdgcn_rcpf(Qf * P);
        const float De = __expf(-2.f * cn);
        const float hn_new =
            (1.f - De) * __builtin_amdgcn_rcpf((1.f + Ce) * (1.f + De));
        const bool act = (t < mydeg[nt]);
        if (act) cst[gt][nt] = cn;
        const float hn = act ? hn_new : hprev[gt][nt];
        hprev[gt][nt] = hn;
        Hs[nxt][row * 128 + ((w ^ (row & 15)) * 8) + (col & 7)] = f2bf(hn);
      }
    }
    lgkm_barrier();   // single barrier: dbuf writes visible, reads done
  }

  // ---- fused SAGE epilogue: h1n = relu(feat@Ws + hT@Wn + b) * rsqrt(deg) ----
  const bf16* Hf = Hs[maxdeg & 1];
  {
    const int rq = w & 3, cp = w >> 2;
    const int rowA = rq * 16 + l15;               // A-frag row (m index)
    const int ndA = nodes_s[rowA];
    const int ndA2 = (ndA >= 0) ? ndA : 0;        // garbage rows never written
    s16x8 Fa[4], Ha[4];
#pragma unroll
    for (int kt = 0; kt < 4; ++kt) {
      Fa[kt] = ldfrag_f32(featF + (size_t)ndA2 * HIDD + kt * 32 + quad * 8);
      Ha[kt] = ldfrag(Hf + rowA * 128 + (((kt * 4 + quad) ^ l15) * 8));
    }
    int ndC[4]; float nrmC[4];
#pragma unroll
    for (int r = 0; r < 4; ++r) {
      const int rowC = rq * 16 + quad * 4 + r;
      ndC[r] = nodes_s[rowC];
      const int dd = degs_s[rowC];
      nrmC[r] = rsqrtf((float)((dd > 0) ? dd : 1));
    }
#pragma unroll
    for (int cc = 0; cc < 2; ++cc) {
      const int col = (cp * 2 + cc) * 16 + l15;
      f32x4 acc = {0.f, 0.f, 0.f, 0.f};
#pragma unroll
      for (int kt = 0; kt < 4; ++kt) {
        acc = MFMA16(Fa[kt], ldfrag(WsT + col * HIDD + kt * 32 + quad * 8), acc);
        acc = MFMA16(Ha[kt], ldfrag(WnT + col * HIDD + kt * 32 + quad * 8), acc);
      }
      const float bb = b_sage[col];
#pragma unroll
      for (int r = 0; r < 4; ++r)
        if (ndC[r] >= 0)
          h1n[(size_t)ndC[r] * HIDD + col] = f2bf(fmaxf(acc[r] + bb, 0.f) * nrmC[r]);
    }
  }
}

// ------- FUSED: agg gather -> gc GEMM -> GRU -> per-graph pool partial -------
__global__ __launch_bounds__(256) void aggru_kernel(const bf16* __restrict__ h1n,
                                                    const int* __restrict__ nbr_idx,
                                                    const int* __restrict__ deg,
                                                    const int* __restrict__ gids,
                                                    const bf16* __restrict__ WgT,
                                                    const float* __restrict__ b_gc,
                                                    const bf16* __restrict__ WgruB,
                                                    const float* __restrict__ bih,
                                                    const float* __restrict__ bhh,
                                                    float* __restrict__ psums,
                                                    float* __restrict__ pcnts) {
  __shared__ __align__(16) bf16 Ag[64 * 136];     // aggregated rows, padded pitch
  __shared__ __align__(16) bf16 H2[64 * 136];     // h2 tile, padded pitch
  __shared__ int nbrL[64 * 16];                   // [node][t] nbr lists
  __shared__ float psl[2 * GRUH];
  __shared__ float pcl[2];
  const int tid = threadIdx.x;
  const int lane = tid & 63, wave = tid >> 6;
  const int l15 = lane & 15, quad = lane >> 4;
  const int nbb = blockIdx.x * 64;
  const int nb = nbb + wave * 16;

  if (tid < 2 * GRUH) psl[tid] = 0.f;
  if (tid < 2) pcl[tid] = 0.f;

  // stage nbr lists (contiguous copy)
  for (int e = tid; e < 64 * 16; e += 256) {
    const int node = nbb + (e >> 4);
    nbrL[e] = (node < NN) ? nbr_idx[node * MAXD + (e & 15)] : 0;
  }
  __syncthreads();

  // phase A: node-parallel gather. thread -> (node = tid>>2, cols (tid&3)*32..+31)
  {
    const int myn = tid >> 2;
    const int node = nbb + myn;
    const int seg = (tid & 3) * 32;
    const int d = (node < NN) ? deg[node] : 0;
    float accv[32];
#pragma unroll
    for (int k = 0; k < 32; ++k) accv[k] = 0.f;
#pragma unroll 2
    for (int j = 0; j < d; ++j) {
      const int nbr = nbrL[myn * 16 + j];
      const bf16* rp = h1n + (size_t)nbr * HIDD + seg;
#pragma unroll
      for (int f = 0; f < 4; ++f) {
        union { s16x8 v; unsigned u[4]; } t_;
        t_.v = ldfrag(rp + f * 8);
#pragma unroll
        for (int p = 0; p < 4; ++p) {
          accv[f * 8 + 2 * p]     += lo2f(t_.u[p]);
          accv[f * 8 + 2 * p + 1] += hi2f(t_.u[p]);
        }
      }
    }
    const float nm = (d > 0) ? rsqrtf((float)d) : 0.f;
#pragma unroll
    for (int f = 0; f < 4; ++f) {
      union { s16x8 v; bf16 h[8]; } o;
#pragma unroll
      for (int k = 0; k < 8; ++k) o.h[k] = f2bf(accv[f * 8 + k] * nm);
      *(s16x8*)(Ag + myn * 136 + seg + f * 8) = o.v;
    }
  }
  __syncthreads();

  // phase B1: gc GEMM from Ag; h2 = relu(.) -> H2
  s16x8 A[4];
#pragma unroll
  for (int kt = 0; kt < 4; ++kt)
    A[kt] = ldfrag(Ag + (wave * 16 + l15) * 136 + kt * 32 + quad * 8);
  for (int ct = 0; ct < 8; ++ct) {
    const int col = ct * 16 + l15;
    f32x4 acc = {0.f, 0.f, 0.f, 0.f};
#pragma unroll
    for (int kt = 0; kt < 4; ++kt)
      acc = MFMA16(A[kt], ldfrag(WgT + col * HIDD + kt * 32 + quad * 8), acc);
    const float bb = b_gc[col];
#pragma unroll
    for (int r = 0; r < 4; ++r)
      H2[(wave * 16 + quad * 4 + r) * 136 + col] = f2bf(fmaxf(acc[r] + bb, 0.f));
  }
  __syncthreads();

  // phase B2: gru GEMM over rows wave*16 + l15
  s16x8 A2[4];
#pragma unroll
  for (int kt = 0; kt < 4; ++kt)
    A2[kt] = ldfrag(H2 + (wave * 16 + l15) * 136 + kt * 32 + quad * 8);
  f32x4 acc[6];
#pragma unroll
  for (int ct = 0; ct < 6; ++ct) {
    f32x4 a = {0.f, 0.f, 0.f, 0.f};
#pragma unroll
    for (int kt = 0; kt < 4; ++kt)
      a = MFMA16(A2[kt], ldfrag(WgruB + (ct * 16 + l15) * HIDD + kt * 32 + quad * 8), a);
    acc[ct] = a;
  }

  // phase C: gru activation + per-graph accumulate (block spans <=2 graphs)
  const int g0 = gids[nbb];
  int mynode[4], mygs[4];
#pragma unroll
  for (int r = 0; r < 4; ++r) {
    const int nd = nb + quad * 4 + r;
    mynode[r] = nd;
    mygs[r] = (nd < NN) ? (gids[nd] - g0) : 0;
  }
#pragma unroll
  for (int u = 0; u < 2; ++u) {
    const int cu = 16 * u + l15;
    const float br = bih[cu] + bhh[cu];
    const float bz = bih[32 + cu] + bhh[32 + cu];
    const float bni = bih[64 + cu];
    const float bnh = bhh[64 + cu];
#pragma unroll
    for (int r = 0; r < 4; ++r) {
      if (mynode[r] < NN) {
        const float rv = sigf(acc[u][r] + br);
        const float zv = sigf(acc[2 + u][r] + bz);
        const float nv = tanhf_(acc[4 + u][r] + bni + rv * bnh);
        const float v = (1.f - zv) * nv;
        atomicAdd(&psl[mygs[r] * GRUH + cu], v);
        if (u == 0 && l15 == 0) atomicAdd(&pcl[mygs[r]], 1.f);
      }
    }
  }
  __syncthreads();
  if (tid < 2 * GRUH) {
    const int s = tid >> 5, c = tid & 31;
    const float vv = psl[tid];
    if (vv != 0.f && g0 + s < NGRAPH) atomicAdd(&psums[(g0 + s) * GRUH + c], vv);
  }
  if (tid < 2) {
    if (pcl[tid] != 0.f && g0 + tid < NGRAPH) atomicAdd(&pcnts[g0 + tid], pcl[tid]);
  }
}

// ------- final: per-graph mean + classifier -------
__global__ __launch_bounds__(256) void pool_final_kernel(const float* __restrict__ sums,
                                                         const float* __restrict__ cnts,
                                                         const float* __restrict__ Wcls,
                                                         const float* __restrict__ bcls,
                                                         float* __restrict__ out) {
  const int idx = blockIdx.x * blockDim.x + threadIdx.x;
  if (idx >= NGRAPH * NCLSS) return;
  const int g = idx / NCLSS, k = idx % NCLSS;
  const float inv = 1.0f / cnts[g];
  float acc = bcls[k];
#pragma unroll
  for (int cc = 0; cc < GRUH; ++cc)
    acc += sums[g * GRUH + cc] * inv * Wcls[cc * NCLSS + k];
  out[idx] = acc;
}

extern "C" void kernel_launch(void* const* d_in, const int* in_sizes, int n_in,
                              void* d_out, int out_size, void* d_ws, size_t ws_size,
                              hipStream_t stream) {
  const float* feature  = (const float*)d_in[0];
  const int*   nbr_idx  = (const int*)d_in[1];
  const int*   deg      = (const int*)d_in[2];
  const int*   gids     = (const int*)d_in[3];
  const float* lstm_Wih = (const float*)d_in[4];
  const float* lstm_Whh = (const float*)d_in[5];
  const float* lstm_bih = (const float*)d_in[6];
  const float* lstm_bhh = (const float*)d_in[7];
  const float* W_self   = (const float*)d_in[8];
  const float* W_neigh  = (const float*)d_in[9];
  const float* b_sage   = (const float*)d_in[10];
  const float* W_gc     = (const float*)d_in[11];
  const float* b_gc     = (const float*)d_in[12];
  const float* Wih_gru  = (const float*)d_in[13];
  const float* bih_gru  = (const float*)d_in[14];
  const float* bhh_gru  = (const float*)d_in[15];
  const float* W_cls    = (const float*)d_in[16];
  const float* b_cls    = (const float*)d_in[17];

  // workspace: peak ~64.9 MB (within the 65.4 MB proven bound).
  char* ws = (char*)d_ws;
  bf16*  h1nB  = (bf16*)(ws + 0);           // [NN,128] 12.8MB
  bf16*  Gp    = (bf16*)(ws + 12800000);    // [NN,512] 51.2MB (dead after lstm)
  const size_t wo = 64000000;
  bf16*  WihB  = (bf16*)(ws + wo);
  bf16*  WhhB  = (bf16*)(ws + wo + 131072);
  bf16*  WsT   = (bf16*)(ws + wo + 262144);
  bf16*  WnT   = (bf16*)(ws + wo + 294912);
  bf16*  WgT   = (bf16*)(ws + wo + 327680);
  bf16*  WgruB = (bf16*)(ws + wo + 360448);
  float* biasS = (float*)(ws + wo + 385024);
  int*   perm  = (int*)(ws + 64500000);     // 200KB
  int*   histp = (int*)(ws + 64800000);     // [196*17] = 13.3KB
  int*   resv  = (int*)(ws + 64814000);     // [17]
  float* psums = (float*)(ws + 64815000);   // [50][32]
  float* pcnts = (float*)(ws + 64821400);   // [50]

  prep_kernel<<<754, 256, 0, stream>>>(lstm_Wih, lstm_Whh, lstm_bih, lstm_bhh,
                                       W_self, W_neigh, W_gc, Wih_gru, deg,
                                       WihB, WhhB, WsT, WnT, WgT, WgruB, biasS,
                                       histp, resv, psums);
  sg_kernel<<<978, 256, 0, stream>>>(feature, WihB, biasS, Gp, deg, histp, resv, perm);
  lstm_kernel<<<782, 1024, 0, stream>>>(Gp, WhhB, feature, WsT, WnT, b_sage,
                                        nbr_idx, deg, perm, h1nB);
  aggru_kernel<<<782, 256, 0, stream>>>(h1nB, nbr_idx, deg, gids, WgT, b_gc,
                                        WgruB, bih_gru, bhh_gru, psums, pcnts);
  pool_final_kernel<<<2, 256, 0, stream>>>(psums, pcnts, W_cls, b_cls, (float*)d_out);
}

// Round 17
// 363.763 us; speedup vs baseline: 1.0326x; 1.0015x over previous
//
#include <hip/hip_runtime.h>
#include <hip/hip_bf16.h>

// GCN_71451075936314 on gfx950.
// R26: aggru rework on R25 (locked best, 363-364us; lstm ~173 + rest ~191).
//      (a) PERM-ORDERED aggru: natural-order waves gather to max(deg of 16
//          uniform nodes) ~= 15 iters; degree-sorted perm order (already
//          computed for lstm) makes wave degrees near-equal -> ~8.5 iters
//          (~0.57x phase-A work). Pool slab grows to all 50 graphs (6.6KB).
//      (b) Ag/H2 merged: B1 loads A-frags to REGISTERS, each wave owns its
//          16-row band exclusively -> h2 overwrites Ag in place. LDS
//          39.4KB -> 28.4KB -> 4 -> 5 blocks/CU.
//      Everything else R25-exact (7-trans lstm cell, packed-G'', 5 disp).

#define NN     50000
#define HIDD   128
#define MAXD   16
#define NGRAPH 50
#define NCLSS  10
#define GRUH   32

typedef __attribute__((ext_vector_type(8))) short s16x8;    // 8 bf16 (4 VGPRs)
typedef __attribute__((ext_vector_type(4))) float f32x4;
typedef __hip_bfloat16 bf16;

#define MFMA16(a,b,c)  __builtin_amdgcn_mfma_f32_16x16x32_bf16((a),(b),(c),0,0,0)

__device__ __forceinline__ float bf2f(bf16 x) { return __bfloat162float(x); }
__device__ __forceinline__ bf16  f2bf(float x) { return __float2bfloat16(x); }
__device__ __forceinline__ s16x8 ldfrag(const bf16* p) { return *(const s16x8*)p; }

__device__ __forceinline__ s16x8 ldfrag_f32(const float* p) {
  const float4 a = *(const float4*)p;
  const float4 b = *(const float4*)(p + 4);
  union { s16x8 v; bf16 h[8]; } r;
  r.h[0] = f2bf(a.x); r.h[1] = f2bf(a.y); r.h[2] = f2bf(a.z); r.h[3] = f2bf(a.w);
  r.h[4] = f2bf(b.x); r.h[5] = f2bf(b.y); r.h[6] = f2bf(b.z); r.h[7] = f2bf(b.w);
  return r.v;
}

__device__ __forceinline__ float sigf(float x) {
  return __builtin_amdgcn_rcpf(1.0f + __expf(-x));
}
__device__ __forceinline__ float tanhf_(float x) {
  return 1.0f - 2.0f * __builtin_amdgcn_rcpf(1.0f + __expf(2.0f * x));
}

__device__ __forceinline__ unsigned packbf2(float a, float b) {
  union { bf16 h; unsigned short u; } x, y;
  x.h = f2bf(a); y.h = f2bf(b);
  return (unsigned)x.u | ((unsigned)y.u << 16);
}
__device__ __forceinline__ float lo2f(unsigned u) { return __uint_as_float(u << 16); }
__device__ __forceinline__ float hi2f(unsigned u) { return __uint_as_float(u & 0xffff0000u); }

// barrier that drains LDS ops only — global loads stay in flight
__device__ __forceinline__ void lgkm_barrier() {
  asm volatile("s_waitcnt lgkmcnt(0)\n\ts_barrier" ::: "memory");
}

// ------- prep: weight casts/transposes + bias fold + partial hist + zeroing -------
__global__ __launch_bounds__(256) void prep_kernel(const float* __restrict__ Wih,
                            const float* __restrict__ Whh, const float* __restrict__ bih,
                            const float* __restrict__ bhh, const float* __restrict__ Wself,
                            const float* __restrict__ Wneigh, const float* __restrict__ Wgc,
                            const float* __restrict__ Wgru, const int* __restrict__ deg,
                            bf16* WihB, bf16* WhhB, bf16* WsT, bf16* WnT,
                            bf16* WgT, bf16* WgruB, float* biasS,
                            int* histp, int* resv, float* psums) {
  __shared__ int lh[17];
  const int tid = threadIdx.x;
  if (blockIdx.x < 196) {
    if (tid < 17) lh[tid] = 0;
    __syncthreads();
    const int i = blockIdx.x * 256 + tid;
    if (i < NN) atomicAdd(&lh[deg[i]], 1);
    __syncthreads();
    if (tid < 17) histp[blockIdx.x * 17 + tid] = lh[tid];
  }
  if (blockIdx.x == 0) {
    for (int i = tid; i < 17; i += 256) resv[i] = 0;
    for (int i = tid; i < NGRAPH * GRUH + NGRAPH; i += 256) psums[i] = 0.f;
  }
  const int total = 2 * 65536 + 3 * 16384 + 12288 + 512;   // 193024
  int stride = gridDim.x * blockDim.x;
  for (int idx = blockIdx.x * blockDim.x + threadIdx.x; idx < total; idx += stride) {
    int j = idx;
    if (j < 65536) { WihB[j] = f2bf(Wih[j]); continue; }
    j -= 65536;
    if (j < 65536) { WhhB[j] = f2bf(Whh[j]); continue; }
    j -= 65536;
    if (j < 16384) { int c = j >> 7, k = j & 127; WsT[j] = f2bf(Wself[k * HIDD + c]); continue; }
    j -= 16384;
    if (j < 16384) { int c = j >> 7, k = j & 127; WnT[j] = f2bf(Wneigh[k * HIDD + c]); continue; }
    j -= 16384;
    if (j < 16384) { int c = j >> 7, k = j & 127; WgT[j] = f2bf(Wgc[k * HIDD + c]); continue; }
    j -= 16384;
    if (j < 12288) { WgruB[j] = f2bf(Wgru[j]); continue; }
    j -= 12288;
    biasS[j] = bih[j] + bhh[j];
  }
}

// ------- sg: blocks 0..781 = G-GEMM; blocks 782..977 = scatter (counting sort) -------
__global__ __launch_bounds__(256) void sg_kernel(const float* __restrict__ featF,
                                                 const bf16* __restrict__ WihB,
                                                 const float* __restrict__ biasS,
                                                 bf16* __restrict__ Gp,
                                                 const int* __restrict__ deg,
                                                 const int* __restrict__ histp,
                                                 int* __restrict__ resv,
                                                 int* __restrict__ perm) {
  const int tid = threadIdx.x;
  if (blockIdx.x >= 782) {
    // ---------------- scatter (counting sort by degree, DESCENDING) ----------------
    __shared__ int lh[17], lbase[17], lpos[17], gh[17];
    const int sb = blockIdx.x - 782;
    if (tid < 17) { lh[tid] = 0; lpos[tid] = 0; }
    __syncthreads();
    const int i = sb * 256 + tid;
    const int d = (i < NN) ? deg[i] : -1;
    if (d >= 0) atomicAdd(&lh[d], 1);
    __syncthreads();
    if (tid < 17) {
      int s = 0;
      for (int b = 0; b < 196; ++b) s += histp[b * 17 + tid];
      gh[tid] = s;
    }
    __syncthreads();
    if (tid < 17) {
      int pre = 0;
      for (int k = tid + 1; k < 17; ++k) pre += gh[k];   // descending: larger degs first
      lbase[tid] = pre + (lh[tid] ? atomicAdd(&resv[tid], lh[tid]) : 0);
    }
    __syncthreads();
    if (d >= 0) {
      const int p = lbase[d] + atomicAdd(&lpos[d], 1);
      perm[p] = i;
    }
    return;
  }
  // ---------------- G-GEMM: 2 passes of 32 rows through LDS, coalesced write ----------------
  __shared__ __align__(16) bf16 Gs[32][520];    // 33.3KB, pad 520
  const int lane = tid & 63, wave = tid >> 6;
  const int l15 = lane & 15, quad = lane >> 4;
  const int nb = blockIdx.x * 64;

  s16x8 Bx[4][4];
#pragma unroll
  for (int nt = 0; nt < 4; ++nt) {
    int arow = nb + nt * 16 + l15; if (arow >= NN) arow = NN - 1;
#pragma unroll
    for (int kt = 0; kt < 4; ++kt)
      Bx[nt][kt] = ldfrag_f32(featF + (size_t)arow * HIDD + kt * 32 + quad * 8);
  }

#pragma unroll
  for (int pass = 0; pass < 2; ++pass) {
    for (int hg = wave * 8; hg < wave * 8 + 8; ++hg) {
      const int wr = (l15 & 3) * HIDD + hg * 4 + (l15 >> 2);
      s16x8 Aw[4];
#pragma unroll
      for (int kt = 0; kt < 4; ++kt)
        Aw[kt] = ldfrag(WihB + (size_t)wr * HIDD + kt * 32 + quad * 8);
      const int hcol = hg * 4 + quad;
      const int gbase = (hcol >> 3) * 32 + (hcol & 3) * 8 + ((hcol >> 2) & 1) * 4;
      float b0 = biasS[0 * HIDD + hcol], b1 = biasS[1 * HIDD + hcol];
      float b2 = biasS[2 * HIDD + hcol], b3 = biasS[3 * HIDD + hcol];
#pragma unroll
      for (int nt2 = 0; nt2 < 2; ++nt2) {
        const int nt = pass * 2 + nt2;
        f32x4 acc = {0.f, 0.f, 0.f, 0.f};
#pragma unroll
        for (int kt = 0; kt < 4; ++kt)
          acc = MFMA16(Aw[kt], Bx[nt][kt], acc);
        unsigned u0 = packbf2(acc[0] + b0, acc[1] + b1);
        unsigned u1 = packbf2(acc[2] + b2, acc[3] + b3);
        *(uint2*)(&Gs[nt2 * 16 + l15][gbase]) = make_uint2(u0, u1);
      }
    }
    __syncthreads();
    for (int e = tid; e < 2048; e += 256) {
      const int r = e >> 6, off = (e & 63) * 8;
      const int node = nb + pass * 32 + r;
      if (node < NN)
        *(s16x8*)(Gp + (size_t)node * 512 + off) = *(const s16x8*)(&Gs[r][off]);
    }
    __syncthreads();
  }
}

// ---------------- LSTM recurrence + fused SAGE epilogue ----------------
// 1024 thr / 16 waves / 64 nodes. R13 recurrence; packed-G'' single 16B
// gather per node per thread. Cell uses 7-trans common-denominator form.
__global__ __launch_bounds__(1024, 4) void lstm_kernel(const bf16* __restrict__ Gp,
                                                       const bf16* __restrict__ WhhB,
                                                       const float* __restrict__ featF,
                                                       const bf16* __restrict__ WsT,
                                                       const bf16* __restrict__ WnT,
                                                       const float* __restrict__ b_sage,
                                                       const int* __restrict__ nbr_idx,
                                                       const int* __restrict__ deg,
                                                       const int* __restrict__ perm,
                                                       bf16* __restrict__ h1n) {
  __shared__ __align__(16) bf16 Hs[2][64 * 128];  // 32KB: h dbuf, oct-xor swizzled
  __shared__ int nbr_s[16 * 64];                  // [t][row]
  __shared__ int nodes_s[64];
  __shared__ int degs_s[64];

  const int tid = threadIdx.x;
  const int lane = tid & 63, w = tid >> 6;        // w = hcol-block 0..15
  const int l15 = lane & 15, quad = lane >> 4;
  const int base = blockIdx.x * 64;

  if (tid < 64) {
    const int gi = base + tid;
    const int nd = (gi < NN) ? perm[gi] : -1;
    nodes_s[tid] = nd;
    degs_s[tid] = (nd >= 0) ? deg[nd] : 0;
  }
  __syncthreads();
  {
    const int row = tid & 63, t = tid >> 6;       // exactly one entry per thread
    const int nd = nodes_s[row];
    nbr_s[t * 64 + row] = (nd >= 0) ? nbr_idx[nd * MAXD + t] : 0;
  }

  // pinned Whh packed frags: vrow v=l15 -> Whh row (v&3)*128 + w*8 + gt*4 + (v>>2)
  s16x8 Bh[2][4];
#pragma unroll
  for (int gt = 0; gt < 2; ++gt) {
    const int wr = (l15 & 3) * HIDD + w * 8 + gt * 4 + (l15 >> 2);
#pragma unroll
    for (int kt = 0; kt < 4; ++kt) {
      Bh[gt][kt] = ldfrag(WhhB + (size_t)wr * HIDD + kt * 32 + quad * 8);
      asm volatile("" : "+v"(Bh[gt][kt]));
    }
  }

  __syncthreads();                                // nbr_s visible
  const int maxdeg = degs_s[0];                   // descending sort -> block max

  int mydeg[4];
#pragma unroll
  for (int nt = 0; nt < 4; ++nt) mydeg[nt] = degs_s[nt * 16 + l15];

  // per-thread packed G'' element offset (16B = both gt chunks)
  const int gofs = w * 32 + quad * 8;

  float cst[2][4] = {{0.f, 0.f, 0.f, 0.f}, {0.f, 0.f, 0.f, 0.f}};
  float hprev[2][4] = {{0.f, 0.f, 0.f, 0.f}, {0.f, 0.f, 0.f, 0.f}};

  for (int t = 0; t < maxdeg; ++t) {
    const int cur = t & 1, nxt = cur ^ 1;

    // gather x-gates: ONE 16B load per node
    uint2 gx[2][4];
#pragma unroll
    for (int nt = 0; nt < 4; ++nt) {
      const int nb1 = nbr_s[t * 64 + nt * 16 + l15];
      const uint4 g4 = *(const uint4*)(Gp + (size_t)nb1 * 512 + gofs);
      gx[0][nt] = make_uint2(g4.x, g4.y);
      gx[1][nt] = make_uint2(g4.z, g4.w);
    }

    f32x4 acc[2][4];
#pragma unroll
    for (int gt = 0; gt < 2; ++gt)
#pragma unroll
      for (int nt = 0; nt < 4; ++nt) acc[gt][nt] = (f32x4){0.f, 0.f, 0.f, 0.f};

    // h-part: gates += Whh_packed @ h^T  (skip at t=0: h0 = 0)
    if (t > 0) {
      __builtin_amdgcn_s_setprio(1);
#pragma unroll
      for (int kt = 0; kt < 4; ++kt) {
#pragma unroll
        for (int nt = 0; nt < 4; ++nt) {
          const int row = nt * 16 + l15;
          const s16x8 ah = ldfrag(Hs[cur] + row * 128 + (((kt * 4 + quad) ^ l15) * 8));
#pragma unroll
          for (int gt = 0; gt < 2; ++gt)
            acc[gt][nt] = MFMA16(Bh[gt][kt], ah, acc[gt][nt]);
        }
      }
      __builtin_amdgcn_s_setprio(0);
    }

    // elementwise cell (7-trans common-denominator form)
#pragma unroll
    for (int gt = 0; gt < 2; ++gt) {
      const int col = w * 8 + gt * 4 + quad;
#pragma unroll
      for (int nt = 0; nt < 4; ++nt) {
        const int row = nt * 16 + l15;
        const uint2 g = gx[gt][nt];
        const float g_i = acc[gt][nt][0] + lo2f(g.x);
        const float g_f = acc[gt][nt][1] + hi2f(g.x);
        const float g_g = acc[gt][nt][2] + lo2f(g.y);
        const float g_o = acc[gt][nt][3] + hi2f(g.y);
        const float Ae = __expf(-g_i);
        const float Fe = __expf(-g_f);
        const float Be = __expf(-2.f * g_g);
        const float Ce = __expf(-g_o);
        const float Qf = 1.f + Fe;
        const float P  = (1.f + Ae) * (1.f + Be);
        const float num = cst[gt][nt] * P + (1.f - Be) * Qf;
        const float cn = num * __builtin_amdgcn_rcpf(Qf * P);
        const float De = __expf(-2.f * cn);
        const float hn_new =
            (1.f - De) * __builtin_amdgcn_rcpf((1.f + Ce) * (1.f + De));
        const bool act = (t < mydeg[nt]);
        if (act) cst[gt][nt] = cn;
        const float hn = act ? hn_new : hprev[gt][nt];
        hprev[gt][nt] = hn;
        Hs[nxt][row * 128 + ((w ^ (row & 15)) * 8) + (col & 7)] = f2bf(hn);
      }
    }
    lgkm_barrier();   // single barrier: dbuf writes visible, reads done
  }

  // ---- fused SAGE epilogue: h1n = relu(feat@Ws + hT@Wn + b) * rsqrt(deg) ----
  const bf16* Hf = Hs[maxdeg & 1];
  {
    const int rq = w & 3, cp = w >> 2;
    const int rowA = rq * 16 + l15;               // A-frag row (m index)
    const int ndA = nodes_s[rowA];
    const int ndA2 = (ndA >= 0) ? ndA : 0;        // garbage rows never written
    s16x8 Fa[4], Ha[4];
#pragma unroll
    for (int kt = 0; kt < 4; ++kt) {
      Fa[kt] = ldfrag_f32(featF + (size_t)ndA2 * HIDD + kt * 32 + quad * 8);
      Ha[kt] = ldfrag(Hf + rowA * 128 + (((kt * 4 + quad) ^ l15) * 8));
    }
    int ndC[4]; float nrmC[4];
#pragma unroll
    for (int r = 0; r < 4; ++r) {
      const int rowC = rq * 16 + quad * 4 + r;
      ndC[r] = nodes_s[rowC];
      const int dd = degs_s[rowC];
      nrmC[r] = rsqrtf((float)((dd > 0) ? dd : 1));
    }
#pragma unroll
    for (int cc = 0; cc < 2; ++cc) {
      const int col = (cp * 2 + cc) * 16 + l15;
      f32x4 acc = {0.f, 0.f, 0.f, 0.f};
#pragma unroll
      for (int kt = 0; kt < 4; ++kt) {
        acc = MFMA16(Fa[kt], ldfrag(WsT + col * HIDD + kt * 32 + quad * 8), acc);
        acc = MFMA16(Ha[kt], ldfrag(WnT + col * HIDD + kt * 32 + quad * 8), acc);
      }
      const float bb = b_sage[col];
#pragma unroll
      for (int r = 0; r < 4; ++r)
        if (ndC[r] >= 0)
          h1n[(size_t)ndC[r] * HIDD + col] = f2bf(fmaxf(acc[r] + bb, 0.f) * nrmC[r]);
    }
  }
}

// ------- FUSED: agg gather -> gc GEMM -> GRU -> per-graph pool partial -------
// PERM-ORDERED blocks (near-uniform degree per wave -> coherent gather
// loops); Ag reused in place for h2 (each wave owns its 16-row band; A-frags
// live in registers before overwrite). Full 50-graph pool slab in LDS.
__global__ __launch_bounds__(256) void aggru_kernel(const bf16* __restrict__ h1n,
                                                    const int* __restrict__ nbr_idx,
                                                    const int* __restrict__ deg,
                                                    const int* __restrict__ gids,
                                                    const int* __restrict__ perm,
                                                    const bf16* __restrict__ WgT,
                                                    const float* __restrict__ b_gc,
                                                    const bf16* __restrict__ WgruB,
                                                    const float* __restrict__ bih,
                                                    const float* __restrict__ bhh,
                                                    float* __restrict__ psums,
                                                    float* __restrict__ pcnts) {
  __shared__ __align__(16) bf16 Ag[64 * 136];     // agg rows -> reused as h2
  __shared__ int nbrL[64 * 16];                   // [node][t] nbr lists
  __shared__ int nodesL[64];
  __shared__ float psl[NGRAPH * GRUH];            // 6.4KB full-graph slab
  __shared__ float pcl[NGRAPH];
  const int tid = threadIdx.x;
  const int lane = tid & 63, wave = tid >> 6;
  const int l15 = lane & 15, quad = lane >> 4;
  const int nbb = blockIdx.x * 64;

  for (int i = tid; i < NGRAPH * GRUH; i += 256) psl[i] = 0.f;
  if (tid < NGRAPH) pcl[tid] = 0.f;
  if (tid < 64) nodesL[tid] = (nbb + tid < NN) ? perm[nbb + tid] : -1;
  __syncthreads();

  // stage nbr lists
  for (int e = tid; e < 64 * 16; e += 256) {
    const int nd = nodesL[e >> 4];
    nbrL[e] = (nd >= 0) ? nbr_idx[nd * MAXD + (e & 15)] : 0;
  }
  __syncthreads();

  // phase A: node-parallel gather. thread -> (slot = tid>>2, cols (tid&3)*32..+31)
  {
    const int myn = tid >> 2;
    const int nd = nodesL[myn];
    const int seg = (tid & 3) * 32;
    const int d = (nd >= 0) ? deg[nd] : 0;
    float accv[32];
#pragma unroll
    for (int k = 0; k < 32; ++k) accv[k] = 0.f;
#pragma unroll 2
    for (int j = 0; j < d; ++j) {
      const int nbr = nbrL[myn * 16 + j];
      const bf16* rp = h1n + (size_t)nbr * HIDD + seg;
#pragma unroll
      for (int f = 0; f < 4; ++f) {
        union { s16x8 v; unsigned u[4]; } t_;
        t_.v = ldfrag(rp + f * 8);
#pragma unroll
        for (int p = 0; p < 4; ++p) {
          accv[f * 8 + 2 * p]     += lo2f(t_.u[p]);
          accv[f * 8 + 2 * p + 1] += hi2f(t_.u[p]);
        }
      }
    }
    const float nm = (d > 0) ? rsqrtf((float)d) : 0.f;
#pragma unroll
    for (int f = 0; f < 4; ++f) {
      union { s16x8 v; bf16 h[8]; } o;
#pragma unroll
      for (int k = 0; k < 8; ++k) o.h[k] = f2bf(accv[f * 8 + k] * nm);
      *(s16x8*)(Ag + myn * 136 + seg + f * 8) = o.v;
    }
  }
  __syncthreads();

  // phase B1: load own-row A frags to REGISTERS, then h2 = relu(.) -> Ag in place
  s16x8 A[4];
#pragma unroll
  for (int kt = 0; kt < 4; ++kt)
    A[kt] = ldfrag(Ag + (wave * 16 + l15) * 136 + kt * 32 + quad * 8);
  __syncthreads();                                // all A-frags in regs before overwrite
  for (int ct = 0; ct < 8; ++ct) {
    const int col = ct * 16 + l15;
    f32x4 acc = {0.f, 0.f, 0.f, 0.f};
#pragma unroll
    for (int kt = 0; kt < 4; ++kt)
      acc = MFMA16(A[kt], ldfrag(WgT + col * HIDD + kt * 32 + quad * 8), acc);
    const float bb = b_gc[col];
#pragma unroll
    for (int r = 0; r < 4; ++r)
      Ag[(wave * 16 + quad * 4 + r) * 136 + col] = f2bf(fmaxf(acc[r] + bb, 0.f));
  }
  __syncthreads();

  // phase B2: gru GEMM over rows wave*16 + l15 (reads h2 from Ag)
  s16x8 A2[4];
#pragma unroll
  for (int kt = 0; kt < 4; ++kt)
    A2[kt] = ldfrag(Ag + (wave * 16 + l15) * 136 + kt * 32 + quad * 8);
  f32x4 acc[6];
#pragma unroll
  for (int ct = 0; ct < 6; ++ct) {
    f32x4 a = {0.f, 0.f, 0.f, 0.f};
#pragma unroll
    for (int kt = 0; kt < 4; ++kt)
      a = MFMA16(A2[kt], ldfrag(WgruB + (ct * 16 + l15) * HIDD + kt * 32 + quad * 8), a);
    acc[ct] = a;
  }

  // phase C: gru activation + per-graph accumulate (full 50-slot slab)
  int mynode[4], mygs[4];
#pragma unroll
  for (int r = 0; r < 4; ++r) {
    const int nd = nodesL[wave * 16 + quad * 4 + r];
    mynode[r] = nd;
    mygs[r] = (nd >= 0) ? gids[nd] : 0;
  }
#pragma unroll
  for (int u = 0; u < 2; ++u) {
    const int cu = 16 * u + l15;
    const float br = bih[cu] + bhh[cu];
    const float bz = bih[32 + cu] + bhh[32 + cu];
    const float bni = bih[64 + cu];
    const float bnh = bhh[64 + cu];
#pragma unroll
    for (int r = 0; r < 4; ++r) {
      if (mynode[r] >= 0) {
        const float rv = sigf(acc[u][r] + br);
        const float zv = sigf(acc[2 + u][r] + bz);
        const float nv = tanhf_(acc[4 + u][r] + bni + rv * bnh);
        const float v = (1.f - zv) * nv;
        atomicAdd(&psl[mygs[r] * GRUH + cu], v);
        if (u == 0 && l15 == 0) atomicAdd(&pcl[mygs[r]], 1.f);
      }
    }
  }
  __syncthreads();
  for (int i = tid; i < NGRAPH * GRUH; i += 256) {
    const float vv = psl[i];
    if (vv != 0.f) atomicAdd(&psums[i], vv);
  }
  if (tid < NGRAPH && pcl[tid] != 0.f) atomicAdd(&pcnts[tid], pcl[tid]);
}

// ------- final: per-graph mean + classifier -------
__global__ __launch_bounds__(256) void pool_final_kernel(const float* __restrict__ sums,
                                                         const float* __restrict__ cnts,
                                                         const float* __restrict__ Wcls,
                                                         const float* __restrict__ bcls,
                                                         float* __restrict__ out) {
  const int idx = blockIdx.x * blockDim.x + threadIdx.x;
  if (idx >= NGRAPH * NCLSS) return;
  const int g = idx / NCLSS, k = idx % NCLSS;
  const float inv = 1.0f / cnts[g];
  float acc = bcls[k];
#pragma unroll
  for (int cc = 0; cc < GRUH; ++cc)
    acc += sums[g * GRUH + cc] * inv * Wcls[cc * NCLSS + k];
  out[idx] = acc;
}

extern "C" void kernel_launch(void* const* d_in, const int* in_sizes, int n_in,
                              void* d_out, int out_size, void* d_ws, size_t ws_size,
                              hipStream_t stream) {
  const float* feature  = (const float*)d_in[0];
  const int*   nbr_idx  = (const int*)d_in[1];
  const int*   deg      = (const int*)d_in[2];
  const int*   gids     = (const int*)d_in[3];
  const float* lstm_Wih = (const float*)d_in[4];
  const float* lstm_Whh = (const float*)d_in[5];
  const float* lstm_bih = (const float*)d_in[6];
  const float* lstm_bhh = (const float*)d_in[7];
  const float* W_self   = (const float*)d_in[8];
  const float* W_neigh  = (const float*)d_in[9];
  const float* b_sage   = (const float*)d_in[10];
  const float* W_gc     = (const float*)d_in[11];
  const float* b_gc     = (const float*)d_in[12];
  const float* Wih_gru  = (const float*)d_in[13];
  const float* bih_gru  = (const float*)d_in[14];
  const float* bhh_gru  = (const float*)d_in[15];
  const float* W_cls    = (const float*)d_in[16];
  const float* b_cls    = (const float*)d_in[17];

  // workspace: peak ~64.9 MB (within the 65.4 MB proven bound).
  char* ws = (char*)d_ws;
  bf16*  h1nB  = (bf16*)(ws + 0);           // [NN,128] 12.8MB
  bf16*  Gp    = (bf16*)(ws + 12800000);    // [NN,512] 51.2MB (dead after lstm)
  const size_t wo = 64000000;
  bf16*  WihB  = (bf16*)(ws + wo);
  bf16*  WhhB  = (bf16*)(ws + wo + 131072);
  bf16*  WsT   = (bf16*)(ws + wo + 262144);
  bf16*  WnT   = (bf16*)(ws + wo + 294912);
  bf16*  WgT   = (bf16*)(ws + wo + 327680);
  bf16*  WgruB = (bf16*)(ws + wo + 360448);
  float* biasS = (float*)(ws + wo + 385024);
  int*   perm  = (int*)(ws + 64500000);     // 200KB
  int*   histp = (int*)(ws + 64800000);     // [196*17] = 13.3KB
  int*   resv  = (int*)(ws + 64814000);     // [17]
  float* psums = (float*)(ws + 64815000);   // [50][32]
  float* pcnts = (float*)(ws + 64821400);   // [50]

  prep_kernel<<<754, 256, 0, stream>>>(lstm_Wih, lstm_Whh, lstm_bih, lstm_bhh,
                                       W_self, W_neigh, W_gc, Wih_gru, deg,
                                       WihB, WhhB, WsT, WnT, WgT, WgruB, biasS,
                                       histp, resv, psums);
  sg_kernel<<<978, 256, 0, stream>>>(feature, WihB, biasS, Gp, deg, histp, resv, perm);
  lstm_kernel<<<782, 1024, 0, stream>>>(Gp, WhhB, feature, WsT, WnT, b_sage,
                                        nbr_idx, deg, perm, h1nB);
  aggru_kernel<<<782, 256, 0, stream>>>(h1nB, nbr_idx, deg, gids, perm, WgT, b_gc,
                                        WgruB, bih_gru, bhh_gru, psums, pcnts);
  pool_final_kernel<<<2, 256, 0, stream>>>(psums, pcnts, W_cls, b_cls, (float*)d_out);
}